// Round 3
// baseline (489.130 us; speedup 1.0000x reference)
//
#include <hip/hip_runtime.h>
#include <math.h>

// Problem constants
#define NMASK 1024
#define HH 256
#define WW 256
#define HW 65536            // H*W
#define OUT_ELEMS 67108864  // NMASK*HW
#define ROWS_CAP 512        // suppression rows precomputed in LDS (nv rarely >150)

// ---------------------------------------------------------------------------
// Kernel A: per-half-mask stats. 2 blocks per mask (rows [0,128) / [128,256)),
// 256 threads, 32 float4/thread. Partials: hi=count(>1), lo=count(>-1),
// bbox of (>0) with absolute y coords. Combined later in scorerank.
// ---------------------------------------------------------------------------
__global__ __launch_bounds__(256) void stats_kernel(
    const float* __restrict__ logits, int* __restrict__ pstats) {
  const int m = blockIdx.x >> 1;
  const int h = blockIdx.x & 1;
  const int t = threadIdx.x;
  const float4* __restrict__ p =
      (const float4*)(logits + (size_t)m * HW + (size_t)h * (HW / 2));

  int hi = 0, lo = 0;
  int miny = HH, maxy = -1, minx = WW, maxx = -1;

#pragma unroll 4
  for (int k = 0; k < 32; ++k) {
    const int f = k * 256 + t;          // float4 index within half [0,8192)
    const float4 v = p[f];
    const int y = (f >> 6) + h * 128;   // 64 float4 per row; absolute y
    const int x0 = (f & 63) << 2;

    const bool p0 = v.x > 0.0f, p1 = v.y > 0.0f, p2 = v.z > 0.0f, p3 = v.w > 0.0f;
    hi += (v.x > 1.0f) + (v.y > 1.0f) + (v.z > 1.0f) + (v.w > 1.0f);
    lo += (v.x > -1.0f) + (v.y > -1.0f) + (v.z > -1.0f) + (v.w > -1.0f);
    if (p0 | p1 | p2 | p3) {
      miny = min(miny, y);
      maxy = max(maxy, y);
      if (p0) { minx = min(minx, x0);     maxx = max(maxx, x0); }
      if (p1) { minx = min(minx, x0 + 1); maxx = max(maxx, x0 + 1); }
      if (p2) { minx = min(minx, x0 + 2); maxx = max(maxx, x0 + 2); }
      if (p3) { minx = min(minx, x0 + 3); maxx = max(maxx, x0 + 3); }
    }
  }

  // wave (64-lane) reduction
  for (int off = 32; off; off >>= 1) {
    hi += __shfl_down(hi, off);
    lo += __shfl_down(lo, off);
    miny = min(miny, __shfl_down(miny, off));
    maxy = max(maxy, __shfl_down(maxy, off));
    minx = min(minx, __shfl_down(minx, off));
    maxx = max(maxx, __shfl_down(maxx, off));
  }

  __shared__ int red[4][6];
  const int wv = t >> 6, ln = t & 63;
  if (ln == 0) {
    red[wv][0] = hi;  red[wv][1] = lo;
    red[wv][2] = miny; red[wv][3] = maxy;
    red[wv][4] = minx; red[wv][5] = maxx;
  }
  __syncthreads();
  if (t == 0) {
    int H2 = 0, L2 = 0, mny = HH, mxy = -1, mnx = WW, mxx = -1;
    for (int w = 0; w < 4; ++w) {
      H2 += red[w][0]; L2 += red[w][1];
      mny = min(mny, red[w][2]); mxy = max(mxy, red[w][3]);
      mnx = min(mnx, red[w][4]); mxx = max(mxx, red[w][5]);
    }
    int* s = pstats + blockIdx.x * 8;
    s[0] = H2; s[1] = L2; s[2] = mny; s[3] = mxy; s[4] = mnx; s[5] = mxx;
  }
}

// ---------------------------------------------------------------------------
// Kernel B: fused score+rank. Block i combines both stat halves for all 1024
// masks into LDS scores, computes stable rank of mask i (score desc, index
// asc), and scatters box/validity into sorted arrays. Writes boxes_out[i].
// ---------------------------------------------------------------------------
__global__ __launch_bounds__(256) void scorerank_kernel(
    const float* __restrict__ iou_preds, const int* __restrict__ pstats,
    float* __restrict__ sbox, int* __restrict__ sidx, int* __restrict__ svalid,
    float* __restrict__ boxes_out) {
  __shared__ float ssc[NMASK];
  const int b = blockIdx.x;
  const int t = threadIdx.x;

  for (int j = t; j < NMASK; j += 256) {
    const int* a = pstats + (2 * j) * 8;
    const int* c = pstats + (2 * j + 1) * 8;
    const int hi = a[0] + c[0];
    const int lo = a[1] + c[1];
    const float stab = (float)hi / fmaxf((float)lo, 1.0f);
    const float iv = iou_preds[j];
    const bool valid = (iv > 0.88f) && (stab >= 0.95f);
    ssc[j] = valid ? iv : -INFINITY;
  }
  __syncthreads();

  const float si = ssc[b];
  int r = 0;
  for (int j = t; j < NMASK; j += 256) {
    const float sj = ssc[j];
    r += (sj > si) || (sj == si && j < b);
  }
  for (int off = 32; off; off >>= 1) r += __shfl_down(r, off);
  __shared__ int red[4];
  if ((t & 63) == 0) red[t >> 6] = r;
  __syncthreads();
  if (t == 0) {
    const int rank = red[0] + red[1] + red[2] + red[3];
    const int* a = pstats + (2 * b) * 8;
    const int* c = pstats + (2 * b + 1) * 8;
    const int mny = min(a[2], c[2]), mxy = max(a[3], c[3]);
    const int mnx = min(a[4], c[4]), mxx = max(a[5], c[5]);
    float bx0, by0, bx1, by1;
    if (mxy < 0) { bx0 = by0 = bx1 = by1 = 0.0f; }
    else { bx0 = (float)mnx; by0 = (float)mny; bx1 = (float)mxx; by1 = (float)mxy; }
    sidx[rank] = b;
    svalid[rank] = (si != -INFINITY) ? 1 : 0;
    sbox[rank * 4 + 0] = bx0; sbox[rank * 4 + 1] = by0;
    sbox[rank * 4 + 2] = bx1; sbox[rank * 4 + 3] = by1;
    boxes_out[b * 4 + 0] = bx0; boxes_out[b * 4 + 1] = by0;
    boxes_out[b * 4 + 2] = bx1; boxes_out[b * 4 + 3] = by1;
  }
}

// ---------------------------------------------------------------------------
// Helper: IoU suppression bit for sorted pair (i, j).
__device__ __forceinline__ bool supp_bit(const float* bx, int i, int j) {
  const float ax0 = bx[i * 4 + 0], ay0 = bx[i * 4 + 1];
  const float ax1 = bx[i * 4 + 2], ay1 = bx[i * 4 + 3];
  const float bx0 = bx[j * 4 + 0], by0 = bx[j * 4 + 1];
  const float bx1 = bx[j * 4 + 2], by1 = bx[j * 4 + 3];
  const float x0 = fmaxf(ax0, bx0), y0 = fmaxf(ay0, by0);
  const float x1 = fminf(ax1, bx1), y1 = fminf(ay1, by1);
  const float inter = fmaxf(x1 - x0, 0.0f) * fmaxf(y1 - y0, 0.0f);
  const float aa = fmaxf(ax1 - ax0, 0.0f) * fmaxf(ay1 - ay0, 0.0f);
  const float ab = fmaxf(bx1 - bx0, 0.0f) * fmaxf(by1 - by0, 0.0f);
  const float iou = inter / fmaxf(aa + ab - inter, 1e-6f);
  return (iou > 0.7f) && (j > i);
}

// ---------------------------------------------------------------------------
// Kernel C: fused IoU-matrix + greedy NMS, single block of 1024 threads.
// Suppression rows for ranks [0, ROWS_CAP) built in LDS by 16 waves in
// parallel; greedy pass on wave 0 with keep bits in 16 lane registers.
// Kept-i >= ROWS_CAP (essentially never) computes its row on the fly.
// ---------------------------------------------------------------------------
__global__ __launch_bounds__(1024) void iounms_kernel(
    const float* __restrict__ sboxg, const int* __restrict__ sidxg,
    const int* __restrict__ svalidg, const float* __restrict__ iou_preds,
    float* __restrict__ gated, float* __restrict__ keep_out) {
  __shared__ float bx[NMASK * 4];                       // 16 KB
  __shared__ int sv[NMASK];                             // 4 KB
  __shared__ int si[NMASK];                             // 4 KB
  __shared__ unsigned long long rows[ROWS_CAP * 16];    // 64 KB
  __shared__ unsigned long long keepw[16];

  const int t = threadIdx.x;
  const int wave = t >> 6, lane = t & 63;

  for (int k = t; k < NMASK * 4; k += 1024) bx[k] = sboxg[k];
  for (int k = t; k < NMASK; k += 1024) { sv[k] = svalidg[k]; si[k] = sidxg[k]; }
  __syncthreads();

  // Build suppression rows: wave w handles rows i = w, w+16, w+32, ...
  for (int i = wave; i < ROWS_CAP; i += 16) {
    if (!sv[i]) continue;  // invalid rows are never kept -> never read
    for (int c = 0; c < 16; ++c) {
      const int j = c * 64 + lane;
      const unsigned long long b = __ballot(supp_bit(bx, i, j));
      if (lane == 0) rows[i * 16 + c] = b;
    }
  }
  __syncthreads();

  // Greedy NMS on wave 0.
  if (wave == 0) {
    unsigned long long keepword = 0ull;
    int nv = 0;
    for (int c = 0; c < 16; ++c) {
      const unsigned long long b = __ballot(sv[c * 64 + lane] != 0);
      if (lane == c) keepword = b;
      nv += (int)__popcll(b);
    }
    for (int i = 0; i < nv; ++i) {
      const int w = i >> 6, bit = i & 63;
      const unsigned long long kw = __shfl(keepword, w, 64);  // wave-uniform
      if ((kw >> bit) & 1ull) {
        if (i < ROWS_CAP) {
          if (lane < 16) keepword &= ~rows[i * 16 + lane];
        } else {
          // on-the-fly row (cold path; nv > ROWS_CAP essentially never)
          unsigned long long myrow = 0ull;
          for (int c = 0; c < 16; ++c) {
            const int j = c * 64 + lane;
            const unsigned long long b = __ballot(supp_bit(bx, i, j));
            if (lane == c) myrow = b;
          }
          if (lane < 16) keepword &= ~myrow;
        }
      }
    }
    if (lane < 16) keepw[lane] = keepword;
  }
  __syncthreads();

  // Scatter keep / gated back to original order (all 1024 threads).
  const unsigned long long kw = keepw[t >> 6];
  const float kept = ((kw >> (t & 63)) & 1ull) ? 1.0f : 0.0f;
  const int orig = si[t];
  keep_out[orig] = kept;
  gated[orig] = kept * iou_preds[orig];
}

// ---------------------------------------------------------------------------
// Kernel D: out = sigmoid(logits) * gated. Zero-write fast path (no read)
// for gated==0 masks. 8 blocks per mask, 256 thr, 8 float4 per thread.
// ---------------------------------------------------------------------------
__global__ __launch_bounds__(256) void out_kernel(
    const float* __restrict__ logits, const float* __restrict__ gated,
    float* __restrict__ out) {
  const int b = blockIdx.x;
  const int m = b >> 3;
  const float g = gated[m];
  const size_t base4 = (size_t)m * 16384 + (size_t)(b & 7) * 2048;  // float4 units
  const float4* __restrict__ in4 = (const float4*)logits + base4;
  float4* __restrict__ o4 = (float4*)out + base4;
  const int t = threadIdx.x;
  if (g == 0.0f) {
    const float4 z = {0.0f, 0.0f, 0.0f, 0.0f};
#pragma unroll
    for (int k = 0; k < 8; ++k) o4[t + k * 256] = z;
  } else {
#pragma unroll
    for (int k = 0; k < 8; ++k) {
      const float4 v = in4[t + k * 256];
      float4 r;
      r.x = g / (1.0f + __expf(-v.x));
      r.y = g / (1.0f + __expf(-v.y));
      r.z = g / (1.0f + __expf(-v.z));
      r.w = g / (1.0f + __expf(-v.w));
      o4[t + k * 256] = r;
    }
  }
}

// ---------------------------------------------------------------------------
extern "C" void kernel_launch(void* const* d_in, const int* in_sizes, int n_in,
                              void* d_out, int out_size, void* d_ws, size_t ws_size,
                              hipStream_t stream) {
  const float* logits = (const float*)d_in[0];
  const float* iou    = (const float*)d_in[1];

  float* out       = (float*)d_out;
  float* keep_out  = out + OUT_ELEMS;          // 1024 floats
  float* boxes_out = keep_out + NMASK;         // 4096 floats

  // workspace carve (~94 KB)
  char* w = (char*)d_ws;
  int*   pstats = (int*)(w);                 // 2048*8 ints = 65536 B
  float* sbox   = (float*)(w + 65536);       // 4096 f     -> 81920
  int*   sidx   = (int*)(w + 81920);         // 1024 i     -> 86016
  int*   svalid = (int*)(w + 86016);         // 1024 i     -> 90112
  float* gated  = (float*)(w + 90112);       // 1024 f     -> 94208

  stats_kernel<<<NMASK * 2, 256, 0, stream>>>(logits, pstats);
  scorerank_kernel<<<NMASK, 256, 0, stream>>>(iou, pstats, sbox, sidx, svalid, boxes_out);
  iounms_kernel<<<1, 1024, 0, stream>>>(sbox, sidx, svalid, iou, gated, keep_out);
  out_kernel<<<NMASK * 8, 256, 0, stream>>>(logits, gated, out);
}